// Round 1
// baseline (210.885 us; speedup 1.0000x reference)
//
#include <hip/hip_runtime.h>
#include <math.h>
#include <stdint.h>

// tgate_hybrid: B=4,S=4096,DIMS=2048,T=10,K=2.
// R13: remove LDS staging entirely. Theory: vmcnt retires IN ORDER, so the
// frag loads inside compute_chunk (issued after the next chunk's staging
// loads) forced every compiler-inserted frag wait to ALSO drain the next
// chunk's HBM staging -> prefetch distance collapsed to <1 chunk -> ~2 TB/s
// latency-bound equilibrium, independent of load mechanism (explains the
// R7/R10/R11 three-mechanism plateau). Fix: the MFMA A-fragment layout
// (lane reads row lane&15, cols quad*8+32k) is fully coalescable as direct
// per-lane register loads (16 rows x fully-used 64B segments per dwordx4),
// so x goes straight to VGPRs, software-pipelined depth 3 at k-step
// granularity with x+frag issued together per future step (uniform distance,
// no in-order cross-gating; register-slot WAR bounds hoisting to D).
// FP path (bf16 hi/lo split, MFMA order, fold, epilogue) is bit-identical
// to R5..R12 -> absmax must remain exactly 0.00390625.

#define NROWS   16384
#define DIMS_   2048
#define TT      10
#define PIPE_D  3

typedef __attribute__((ext_vector_type(8))) short short8;
typedef __attribute__((ext_vector_type(4))) float f32x4;

__device__ __forceinline__ unsigned short bf16_rne(float f) {
    unsigned int u = __float_as_uint(f);
    unsigned int r = u + 0x7fffu + ((u >> 16) & 1u);
    return (unsigned short)(r >> 16);
}

// ---- k0: build B fragments (unchanged since R5; must stay identical).
__global__ __launch_bounds__(256)
void tgate_k0(const float* __restrict__ W_cls,
              const float* __restrict__ W_sparse,
              const float* __restrict__ W_gates,
              unsigned short* __restrict__ frag)
{
    int t = blockIdx.x * 256 + threadIdx.x;
    int K0   = t >> 7;
    int nt   = (t >> 6) & 1;
    int lane = t & 63;
    int n  = nt * 16 + (lane & 15);
    int kb = K0 * 32 + (lane >> 4) * 8;
    short8 hi, lo;
    #pragma unroll
    for (int j = 0; j < 8; ++j) {
        int k = kb + j;
        float w = 0.0f;
        if (n < 10)      w = W_cls[k * TT + n];
        else if (n < 20) w = W_sparse[k * TT + n - 10];
        else if (n < 30) w = W_gates[k * TT + n - 20];
        unsigned short h = bf16_rne(w);
        float back = __uint_as_float(((unsigned int)h) << 16);
        hi[j] = (short)h;
        lo[j] = (short)bf16_rne(w - back);
    }
    short8* fv = reinterpret_cast<short8*>(frag);
    fv[(K0 * 4 + nt * 2 + 0) * 64 + lane] = hi;
    fv[(K0 * 4 + nt * 2 + 1) * 64 + lane] = lo;
}

// ---- k1: fused full-K MFMA GEMV, direct-to-register pipelined (depth 3)
__global__ __launch_bounds__(256)
void tgate_k1(const float* __restrict__ x,
              const unsigned short* __restrict__ frag,
              const float* __restrict__ b_cls,
              const float* __restrict__ b_sparse,
              const float* __restrict__ b_gates,
              const float* __restrict__ alpha,
              float* __restrict__ out)
{
    // LDS only for the cross-wave fold now: red[8][16][33] + fold[16][33]
    __shared__ alignas(16) float red_lds[8 * 16 * 33 + 16 * 33];

    const int tid   = threadIdx.x;
    const int lane  = tid & 63;
    const int wv    = __builtin_amdgcn_readfirstlane(tid >> 6);
    const int row0  = blockIdx.x * 16;
    const int m     = lane & 15;
    const int quad  = lane >> 4;
    const int cbase = wv * 512;          // wave's contiguous 512-col span

    const short8* fv    = reinterpret_cast<const short8*>(frag);
    // frag slice for this wave's K-span; step k uses fbase[(k*4 + j)*64]
    const short8* fbase = fv + (16 * wv * 4) * 64 + lane;
    // A-fragment address: lane owns row m, col block quad*8; step k at +32k
    const float*  xrow  = x + (size_t)(row0 + m) * DIMS_ + cbase + quad * 8;

    f32x4 acc[2][2];
    #pragma unroll
    for (int h = 0; h < 2; ++h) {
        acc[h][0] = (f32x4){0.f, 0.f, 0.f, 0.f};
        acc[h][1] = (f32x4){0.f, 0.f, 0.f, 0.f};
    }

    // pipeline register slots: x (2 float4) + frag (4 short8) per k-step.
    // Uniform prefetch distance PIPE_D for x AND frag: any wait for step k's
    // data only drains steps <= k (in-order vmcnt), never a younger prefetch.
    float4 xa[PIPE_D], xb[PIPE_D];
    short8 fh0[PIPE_D], fl0[PIPE_D], fh1[PIPE_D], fl1[PIPE_D];

    #pragma unroll
    for (int p = 0; p < PIPE_D; ++p) {
        fh0[p] = fbase[(p * 4 + 0) * 64];
        fl0[p] = fbase[(p * 4 + 1) * 64];
        fh1[p] = fbase[(p * 4 + 2) * 64];
        fl1[p] = fbase[(p * 4 + 3) * 64];
        xa[p]  = *reinterpret_cast<const float4*>(xrow + p * 32);
        xb[p]  = *reinterpret_cast<const float4*>(xrow + p * 32 + 4);
    }

    // 16 k-steps; k<8 -> slice 2wv (acc[0]), k>=8 -> slice 2wv+1 (acc[1]);
    // same K0 order and same 6-MFMA sequence per step as R5..R12.
    #pragma unroll
    for (int k = 0; k < 16; ++k) {
        const int sl = k % PIPE_D;       // compile-time after unroll
        const int h  = k >> 3;

        float f[8] = {xa[sl].x, xa[sl].y, xa[sl].z, xa[sl].w,
                      xb[sl].x, xb[sl].y, xb[sl].z, xb[sl].w};
        short8 ah, al;
        #pragma unroll
        for (int j = 0; j < 8; ++j) {
            unsigned short hh = bf16_rne(f[j]);               // rne hi (R5.. path)
            float back = __uint_as_float(((unsigned int)hh) << 16);
            ah[j] = (short)hh;
            al[j] = (short)bf16_rne(f[j] - back);
        }
        short8 h0 = fh0[sl], l0 = fl0[sl], h1 = fh1[sl], l1 = fl1[sl];

        acc[h][0] = __builtin_amdgcn_mfma_f32_16x16x32_bf16(ah, h0, acc[h][0], 0, 0, 0);
        acc[h][0] = __builtin_amdgcn_mfma_f32_16x16x32_bf16(al, h0, acc[h][0], 0, 0, 0);
        acc[h][0] = __builtin_amdgcn_mfma_f32_16x16x32_bf16(ah, l0, acc[h][0], 0, 0, 0);
        acc[h][1] = __builtin_amdgcn_mfma_f32_16x16x32_bf16(ah, h1, acc[h][1], 0, 0, 0);
        acc[h][1] = __builtin_amdgcn_mfma_f32_16x16x32_bf16(al, h1, acc[h][1], 0, 0, 0);
        acc[h][1] = __builtin_amdgcn_mfma_f32_16x16x32_bf16(ah, l1, acc[h][1], 0, 0, 0);

        if (k + PIPE_D < 16) {
            const int kn = k + PIPE_D;   // refills same slot sl (WAR-bounded)
            fh0[sl] = fbase[(kn * 4 + 0) * 64];
            fl0[sl] = fbase[(kn * 4 + 1) * 64];
            fh1[sl] = fbase[(kn * 4 + 2) * 64];
            fl1[sl] = fbase[(kn * 4 + 3) * 64];
            xa[sl]  = *reinterpret_cast<const float4*>(xrow + kn * 32);
            xb[sl]  = *reinterpret_cast<const float4*>(xrow + kn * 32 + 4);
        }
    }

    // ---- partials to LDS: red[s][row][j], pitch 33 (verbatim since R5)
    float* red = red_lds;
    #pragma unroll
    for (int h = 0; h < 2; ++h) {
        int s = 2 * wv + h;
        #pragma unroll
        for (int r = 0; r < 4; ++r) {
            int row = quad * 4 + r;       // C/D layout (verified m89)
            red[(s * 16 + row) * 33 + m]      = acc[h][0][r];
            red[(s * 16 + row) * 33 + m + 16] = acc[h][1][r];
        }
    }
    __syncthreads();

    // ---- fold: bit-identical (l=0; s=0..7 ascending)
    float* fold = red + 8 * 16 * 33;
    #pragma unroll
    for (int u = 0; u < 2; ++u) {
        int i = tid * 2 + u;
        int row = i >> 5, j = i & 31;
        float a = 0.0f;
        #pragma unroll
        for (int s = 0; s < 8; ++s) a += red[(s * 16 + row) * 33 + j];
        fold[row * 33 + j] = a;
    }
    __syncthreads();

    // ---- epilogue: lanes 0..15 of wave 0 (verbatim since R5)
    if (tid < 16) {
        const float* l = &fold[tid * 33];
        float lc[TT], lsp[TT], g[TT];
        #pragma unroll
        for (int t = 0; t < TT; ++t) {
            lc[t]  = l[t]      + b_cls[t];
            lsp[t] = l[10 + t] + b_sparse[t];
            float lg = l[20 + t] + b_gates[t];
            g[t] = 1.0f / (1.0f + __expf(-lg));
        }
        float mm = lc[0];
        #pragma unroll
        for (int t = 1; t < TT; ++t) mm = fmaxf(mm, lc[t]);
        float esum = 0.0f, gdot = 0.0f;
        #pragma unroll
        for (int t = 0; t < TT; ++t) {
            float e = __expf(lc[t] - mm);
            esum += e;
            gdot = fmaf(g[t], e, gdot);
        }
        float v1 = lsp[0], v2 = -1e30f, gv1 = g[0], gv2 = 0.0f;
        #pragma unroll
        for (int t = 1; t < TT; ++t) {
            if (lsp[t] > v1)      { v2 = v1; gv2 = gv1; v1 = lsp[t]; gv1 = g[t]; }
            else if (lsp[t] > v2) { v2 = lsp[t]; gv2 = g[t]; }
        }
        float s1 = 1.0f / (1.0f + __expf(v2 - v1));
        float s2 = 1.0f - s1;
        float a  = 1.0f / (1.0f + __expf(-alpha[0]));
        float sparse_dot = fmaf(gv1, s1, gv2 * s2);
        out[row0 + tid] = fmaf(a, sparse_dot, (1.0f - a) * (gdot / esum));
    }
}

extern "C" void kernel_launch(void* const* d_in, const int* in_sizes, int n_in,
                              void* d_out, int out_size, void* d_ws, size_t ws_size,
                              hipStream_t stream) {
    const float* x        = (const float*)d_in[0];
    const float* W_cls    = (const float*)d_in[1];
    const float* b_cls    = (const float*)d_in[2];
    const float* W_sparse = (const float*)d_in[3];
    const float* b_sparse = (const float*)d_in[4];
    const float* W_gates  = (const float*)d_in[5];
    const float* b_gates  = (const float*)d_in[6];
    const float* alpha    = (const float*)d_in[7];
    float* out = (float*)d_out;

    unsigned short* frag = (unsigned short*)d_ws;   // 256 KB

    tgate_k0<<<dim3(32), dim3(256), 0, stream>>>(W_cls, W_sparse, W_gates, frag);
    tgate_k1<<<dim3(NROWS / 16), dim3(256), 0, stream>>>(x, frag, b_cls, b_sparse,
                                                         b_gates, alpha, out);
}

// Round 2
// 209.794 us; speedup vs baseline: 1.0052x; 1.0052x over previous
//
#include <hip/hip_runtime.h>
#include <math.h>
#include <stdint.h>

// tgate_hybrid: B=4,S=4096,DIMS=2048,T=10,K=2.
// R14: DRAM-visit-granularity theory. All prior variants (LDS-staged 256B/row
// visits, direct-to-reg 16B-holed visits) plateau at ~2-2.4 TB/s read while
// 1KB-visit copies (m13) and the harness fills hit 6.3-6.8 TB/s: with 16384
// concurrent 8KB-strided row-streams each visited 128-256 B at a time, HBM
// row activations transfer only ~256 B -> ~30% DRAM efficiency. Fix: stage
// each x row-segment with ONE global_load_lds of 64 lanes x 16 B = 1 KB
// CONTIGUOUS per instruction. Per wave: 2 chunks of 16 rows x 256 cols
// (16 KB, pitch 260 floats), single-buffered (stage A -> compute k0..7 ->
// stage B -> compute k8..15); 65 KB LDS/block -> 2 blocks/CU; fold reuses
// the staging LDS. FP path (f[8] values, hi/lo split, 6-MFMA order, per-s
// accumulation ranges, fold, epilogue) is bit-identical to R5..R13 ->
// absmax must remain exactly 0.00390625.

#define NROWS   16384
#define DIMS_   2048
#define TT      10

typedef __attribute__((ext_vector_type(8))) short short8;
typedef __attribute__((ext_vector_type(4))) float f32x4;

__device__ __forceinline__ unsigned short bf16_rne(float f) {
    unsigned int u = __float_as_uint(f);
    unsigned int r = u + 0x7fffu + ((u >> 16) & 1u);
    return (unsigned short)(r >> 16);
}

// ---- k0: build B fragments (unchanged since R5; must stay identical).
__global__ __launch_bounds__(256)
void tgate_k0(const float* __restrict__ W_cls,
              const float* __restrict__ W_sparse,
              const float* __restrict__ W_gates,
              unsigned short* __restrict__ frag)
{
    int t = blockIdx.x * 256 + threadIdx.x;
    int K0   = t >> 7;
    int nt   = (t >> 6) & 1;
    int lane = t & 63;
    int n  = nt * 16 + (lane & 15);
    int kb = K0 * 32 + (lane >> 4) * 8;
    short8 hi, lo;
    #pragma unroll
    for (int j = 0; j < 8; ++j) {
        int k = kb + j;
        float w = 0.0f;
        if (n < 10)      w = W_cls[k * TT + n];
        else if (n < 20) w = W_sparse[k * TT + n - 10];
        else if (n < 30) w = W_gates[k * TT + n - 20];
        unsigned short h = bf16_rne(w);
        float back = __uint_as_float(((unsigned int)h) << 16);
        hi[j] = (short)h;
        lo[j] = (short)bf16_rne(w - back);
    }
    short8* fv = reinterpret_cast<short8*>(frag);
    fv[(K0 * 4 + nt * 2 + 0) * 64 + lane] = hi;
    fv[(K0 * 4 + nt * 2 + 1) * 64 + lane] = lo;
}

// stage one 16-row x 256-col chunk: 16 instrs, each 1 KB CONTIGUOUS within
// one x row (64 lanes x 16 B). LDS dest wave-uniform base + lane*16 ->
// row r lands at buf + r*260 .. +256 floats (pitch 260 for bank spread).
__device__ __forceinline__ void stage_span(const float* __restrict__ x,
                                           float* buf, int row0, int lane,
                                           int colf0)
{
    #pragma unroll
    for (int r = 0; r < 16; ++r) {
        const float* gp = x + (size_t)(row0 + r) * DIMS_ + colf0 + lane * 4;
        __builtin_amdgcn_global_load_lds(
            (const __attribute__((address_space(1))) void*)gp,
            (__attribute__((address_space(3))) void*)(buf + r * 260),
            16, 0, 0);
    }
}

// ---- k1: fused full-K MFMA GEMV, 1KB-visit LDS staging, 2 chunks/wave
__global__ __launch_bounds__(256)
void tgate_k1(const float* __restrict__ x,
              const unsigned short* __restrict__ frag,
              const float* __restrict__ b_cls,
              const float* __restrict__ b_sparse,
              const float* __restrict__ b_gates,
              const float* __restrict__ alpha,
              float* __restrict__ out)
{
    // 4 waves x 16 rows x 260 floats = 66560 B; reused for red/fold (4752 f)
    __shared__ alignas(16) float smem[4 * 4160];

    const int tid   = threadIdx.x;
    const int lane  = tid & 63;
    const int wv    = __builtin_amdgcn_readfirstlane(tid >> 6);
    const int row0  = blockIdx.x * 16;
    const int m     = lane & 15;
    const int quad  = lane >> 4;
    const int cbase = wv * 512;          // wave's contiguous 512-col span

    float* buf = smem + wv * 4160;
    const short8* fv    = reinterpret_cast<const short8*>(frag);
    const short8* fbase = fv + (16 * wv * 4) * 64 + lane;   // step k -> +(k*4+j)*64

    f32x4 acc[2][2];
    #pragma unroll
    for (int h = 0; h < 2; ++h) {
        acc[h][0] = (f32x4){0.f, 0.f, 0.f, 0.f};
        acc[h][1] = (f32x4){0.f, 0.f, 0.f, 0.f};
    }

    // ---- stage chunk A (cols cbase..cbase+256) FIRST (oldest vmem ops)
    stage_span(x, buf, row0, lane, cbase);
    __builtin_amdgcn_sched_barrier(0);   // pin issue order: A before frag

    // frag prefetch for steps 0,1 (8 loads, L2-resident)
    short8 F[2][4];
    #pragma unroll
    for (int p = 0; p < 2; ++p) {
        #pragma unroll
        for (int j = 0; j < 4; ++j)
            F[p][j] = fbase[(p * 4 + j) * 64];
    }
    __builtin_amdgcn_sched_barrier(0);   // pin: frag issued after A, before wait

    // A fully landed when <=8 outstanding (the 8 frag loads)
    __builtin_amdgcn_s_waitcnt(0x0F78);  // vmcnt(8)
    __builtin_amdgcn_sched_barrier(0);   // no ds_read hoists above the wait

    #pragma unroll
    for (int k = 0; k < 16; ++k) {
        if (k == 8) {
            // all A ds_reads retired -> safe to overwrite buffer with B
            __builtin_amdgcn_s_waitcnt(0xC07F);  // lgkmcnt(0)
            __builtin_amdgcn_sched_barrier(0);
            stage_span(x, buf, row0, lane, cbase + 256);
            __builtin_amdgcn_s_waitcnt(0x0F70);  // vmcnt(0): B (+frag 8,9) landed
            __builtin_amdgcn_sched_barrier(0);
        }
        const int h = k >> 3;
        const float* src = buf + m * 260 + (k & 7) * 32 + quad * 8;
        float4 b0 = *reinterpret_cast<const float4*>(src);
        float4 b1 = *reinterpret_cast<const float4*>(src + 4);
        float f[8] = {b0.x, b0.y, b0.z, b0.w, b1.x, b1.y, b1.z, b1.w};
        short8 ah, al;
        #pragma unroll
        for (int j = 0; j < 8; ++j) {
            unsigned short hh = bf16_rne(f[j]);               // rne hi (R5.. path)
            float back = __uint_as_float(((unsigned int)hh) << 16);
            ah[j] = (short)hh;
            al[j] = (short)bf16_rne(f[j] - back);
        }
        short8 h0 = F[k & 1][0], l0 = F[k & 1][1];
        short8 h1 = F[k & 1][2], l1 = F[k & 1][3];

        acc[h][0] = __builtin_amdgcn_mfma_f32_16x16x32_bf16(ah, h0, acc[h][0], 0, 0, 0);
        acc[h][0] = __builtin_amdgcn_mfma_f32_16x16x32_bf16(al, h0, acc[h][0], 0, 0, 0);
        acc[h][0] = __builtin_amdgcn_mfma_f32_16x16x32_bf16(ah, l0, acc[h][0], 0, 0, 0);
        acc[h][1] = __builtin_amdgcn_mfma_f32_16x16x32_bf16(ah, h1, acc[h][1], 0, 0, 0);
        acc[h][1] = __builtin_amdgcn_mfma_f32_16x16x32_bf16(al, h1, acc[h][1], 0, 0, 0);
        acc[h][1] = __builtin_amdgcn_mfma_f32_16x16x32_bf16(ah, l1, acc[h][1], 0, 0, 0);

        if (k + 2 < 16) {                 // refill frag slot (k&1) for step k+2
            #pragma unroll
            for (int j = 0; j < 4; ++j)
                F[k & 1][j] = fbase[((k + 2) * 4 + j) * 64];
        }
    }

    // ---- partials to LDS: red[s][row][j], pitch 33 (verbatim since R5;
    //      red aliases the staging buffer, valid after the barrier)
    float* red = smem;
    __syncthreads();
    #pragma unroll
    for (int h = 0; h < 2; ++h) {
        int s = 2 * wv + h;
        #pragma unroll
        for (int r = 0; r < 4; ++r) {
            int row = quad * 4 + r;       // C/D layout (verified m89)
            red[(s * 16 + row) * 33 + m]      = acc[h][0][r];
            red[(s * 16 + row) * 33 + m + 16] = acc[h][1][r];
        }
    }
    __syncthreads();

    // ---- fold: bit-identical (l=0; s=0..7 ascending)
    float* fold = red + 8 * 16 * 33;
    #pragma unroll
    for (int u = 0; u < 2; ++u) {
        int i = tid * 2 + u;
        int row = i >> 5, j = i & 31;
        float a = 0.0f;
        #pragma unroll
        for (int s = 0; s < 8; ++s) a += red[(s * 16 + row) * 33 + j];
        fold[row * 33 + j] = a;
    }
    __syncthreads();

    // ---- epilogue: lanes 0..15 of wave 0 (verbatim since R5)
    if (tid < 16) {
        const float* l = &fold[tid * 33];
        float lc[TT], lsp[TT], g[TT];
        #pragma unroll
        for (int t = 0; t < TT; ++t) {
            lc[t]  = l[t]      + b_cls[t];
            lsp[t] = l[10 + t] + b_sparse[t];
            float lg = l[20 + t] + b_gates[t];
            g[t] = 1.0f / (1.0f + __expf(-lg));
        }
        float mm = lc[0];
        #pragma unroll
        for (int t = 1; t < TT; ++t) mm = fmaxf(mm, lc[t]);
        float esum = 0.0f, gdot = 0.0f;
        #pragma unroll
        for (int t = 0; t < TT; ++t) {
            float e = __expf(lc[t] - mm);
            esum += e;
            gdot = fmaf(g[t], e, gdot);
        }
        float v1 = lsp[0], v2 = -1e30f, gv1 = g[0], gv2 = 0.0f;
        #pragma unroll
        for (int t = 1; t < TT; ++t) {
            if (lsp[t] > v1)      { v2 = v1; gv2 = gv1; v1 = lsp[t]; gv1 = g[t]; }
            else if (lsp[t] > v2) { v2 = lsp[t]; gv2 = g[t]; }
        }
        float s1 = 1.0f / (1.0f + __expf(v2 - v1));
        float s2 = 1.0f - s1;
        float a  = 1.0f / (1.0f + __expf(-alpha[0]));
        float sparse_dot = fmaf(gv1, s1, gv2 * s2);
        out[row0 + tid] = fmaf(a, sparse_dot, (1.0f - a) * (gdot / esum));
    }
}

extern "C" void kernel_launch(void* const* d_in, const int* in_sizes, int n_in,
                              void* d_out, int out_size, void* d_ws, size_t ws_size,
                              hipStream_t stream) {
    const float* x        = (const float*)d_in[0];
    const float* W_cls    = (const float*)d_in[1];
    const float* b_cls    = (const float*)d_in[2];
    const float* W_sparse = (const float*)d_in[3];
    const float* b_sparse = (const float*)d_in[4];
    const float* W_gates  = (const float*)d_in[5];
    const float* b_gates  = (const float*)d_in[6];
    const float* alpha    = (const float*)d_in[7];
    float* out = (float*)d_out;

    unsigned short* frag = (unsigned short*)d_ws;   // 256 KB

    tgate_k0<<<dim3(32), dim3(256), 0, stream>>>(W_cls, W_sparse, W_gates, frag);
    tgate_k1<<<dim3(NROWS / 16), dim3(256), 0, stream>>>(x, frag, b_cls, b_sparse,
                                                         b_gates, alpha, out);
}